// Round 1
// baseline (122.579 us; speedup 1.0000x reference)
//
#include <hip/hip_runtime.h>
#include <hip/hip_bf16.h>

// Nearest-neighbor 4D upsample (scale=2 on axes T,Z,Y,X).
// in : (2, 8, 8, 16, 64, 64)  f32  = 8,388,608 elems (33.5 MB)
// out: (2, 8, 16, 32, 128,128) f32 = 134,217,728 elems (537 MB)
// Memory-bound streaming: each thread produces one float4 of output
// (4 consecutive x) from one aligned float2 of input (2 consecutive x).

__global__ __launch_bounds__(256) void UpsampleNearest4D_38912403701977_kernel(
    const float* __restrict__ in, float4* __restrict__ out, unsigned total4) {
    unsigned stride = gridDim.x * blockDim.x;
    for (unsigned i = blockIdx.x * blockDim.x + threadIdx.x; i < total4; i += stride) {
        // Decode output coords (in float4 units along x).
        // out dims: nc=16, t=16, z=32, y=128, x=128 (x4 = 32 quads)
        unsigned x4 = i & 31u;
        unsigned r1 = i >> 5;
        unsigned y  = r1 & 127u;
        unsigned r2 = r1 >> 7;
        unsigned z  = r2 & 31u;
        unsigned r3 = r2 >> 5;
        unsigned t  = r3 & 15u;
        unsigned nc = r3 >> 4;            // [0,16)

        // Input coords: halve t,z,y; x input pair starts at 2*x4.
        unsigned in_idx = ((((nc * 8u + (t >> 1)) * 16u + (z >> 1)) * 64u
                            + (y >> 1)) * 64u) + (x4 << 1);
        float2 a = *reinterpret_cast<const float2*>(in + in_idx);  // 8B aligned
        out[i] = make_float4(a.x, a.x, a.y, a.y);
    }
}

extern "C" void kernel_launch(void* const* d_in, const int* in_sizes, int n_in,
                              void* d_out, int out_size, void* d_ws, size_t ws_size,
                              hipStream_t stream) {
    const float* in = (const float*)d_in[0];
    float4* out = (float4*)d_out;
    unsigned total4 = (unsigned)(out_size / 4);   // 33,554,432
    dim3 block(256);
    dim3 grid(2048);
    UpsampleNearest4D_38912403701977_kernel<<<grid, block, 0, stream>>>(in, out, total4);
}

// Round 3
// 91.358 us; speedup vs baseline: 1.3417x; 1.3417x over previous
//
#include <hip/hip_runtime.h>
#include <hip/hip_bf16.h>

// Nearest-neighbor 4D upsample (scale=2 on axes T,Z,Y,X).
// in : (2, 8, 8, 16, 64, 64)  f32  = 8,388,608 elems (33.5 MB)
// out: (2, 8, 16, 32, 128,128) f32 = 134,217,728 elems (537 MB)
//
// R2: same as R1 but with clang native vector type for the nontemporal
// builtin (HIP float4 is a struct and is rejected).
// Each thread reads ONE float2 (2 input x) once, writes all 8 duplicated
// output quads (t,z,y doublings) from registers via nontemporal stores.

typedef float f32x4 __attribute__((ext_vector_type(4)));
typedef float f32x2 __attribute__((ext_vector_type(2)));

__global__ __launch_bounds__(256) void UpsampleNearest4D_38912403701977_kernel(
    const float* __restrict__ in, f32x4* __restrict__ out) {
    unsigned j = blockIdx.x * 256u + threadIdx.x;   // [0, 4,194,304)

    // Decode INPUT coords. Per input row (64 x) there are 32 x-pairs.
    unsigned x4 = j & 31u;          // input x-pair index -> output quad x4
    unsigned r  = j >> 5;
    unsigned y  = r & 63u;  r >>= 6;   // y_in  [0,64)
    unsigned z  = r & 15u;  r >>= 4;   // z_in  [0,16)
    unsigned t  = r & 7u;              // t_in  [0,8)
    unsigned nc = r >> 3;              // n*c   [0,16)

    unsigned in_idx = ((((nc * 8u + t) * 16u + z) * 64u + y) * 64u) + (x4 << 1);
    f32x2 a = *reinterpret_cast<const f32x2*>(in + in_idx);  // 8B aligned
    f32x4 v = { a.x, a.x, a.y, a.y };

    // Output quad index: out dims (16, 16t, 32z, 128y, 128x) -> 32 quads/row.
    unsigned base = ((((nc * 16u + 2u * t) * 32u + 2u * z) * 128u + 2u * y) * 32u) + x4;
    const unsigned dy = 32u;              // +1 y row (in quads)
    const unsigned dz = 128u * 32u;       // +1 z plane
    const unsigned dt = 32u * 128u * 32u; // +1 t volume

    __builtin_nontemporal_store(v, &out[base]);
    __builtin_nontemporal_store(v, &out[base + dy]);
    __builtin_nontemporal_store(v, &out[base + dz]);
    __builtin_nontemporal_store(v, &out[base + dz + dy]);
    __builtin_nontemporal_store(v, &out[base + dt]);
    __builtin_nontemporal_store(v, &out[base + dt + dy]);
    __builtin_nontemporal_store(v, &out[base + dt + dz]);
    __builtin_nontemporal_store(v, &out[base + dt + dz + dy]);
}

extern "C" void kernel_launch(void* const* d_in, const int* in_sizes, int n_in,
                              void* d_out, int out_size, void* d_ws, size_t ws_size,
                              hipStream_t stream) {
    const float* in = (const float*)d_in[0];
    f32x4* out = (f32x4*)d_out;
    // 4,194,304 threads, one float2 -> 8 float4 stores each.
    dim3 block(256);
    dim3 grid(4194304u / 256u);   // 16384 blocks
    UpsampleNearest4D_38912403701977_kernel<<<grid, block, 0, stream>>>(in, out);
}